// Round 7
// baseline (272.919 us; speedup 1.0000x reference)
//
#include <hip/hip_runtime.h>
#include <math.h>

#define HIDDEN 128
#define HEADS 8
#define HDIM 16
#define NSEQ 512
#define NBATCH 4
#define SROW 9          // sS/sB row stride: 9j mod 32 spans all banks in softmax
#define NEGINF (-1e30f)

// v += lane-permuted v (pure VALU DPP).
template <int CTRL>
__device__ __forceinline__ float dppadd(float v) {
    int s = __builtin_amdgcn_update_dpp(0, __float_as_int(v), CTRL, 0xF, 0xF, true);
    return v + __int_as_float(s);
}
#define QUAD_X1  0xB1   // quad_perm [1,0,3,2]  (xor1)
#define QUAD_X2  0x4E   // quad_perm [2,3,0,1]  (xor2)
#define ROW_SHL4 0x104  // lane l receives lane l+4 (xor4 for lanes dseg<4)

// ---------------- Kernel 1: fused Q/K/V projection ----------------
__global__ __launch_bounds__(128) void qkv_proj(
    const float* __restrict__ node,
    const float* __restrict__ Wq, const float* __restrict__ bq,
    const float* __restrict__ Wk, const float* __restrict__ bk,
    const float* __restrict__ Wv, const float* __restrict__ bv,
    float* __restrict__ Q, float* __restrict__ K, float* __restrict__ V)
{
    const int ROWS = 8;
    __shared__ float sX[ROWS][HIDDEN];
    const int row0 = blockIdx.x * ROWS;
    const int tid = threadIdx.x;

    const float4* src = (const float4*)(node + row0 * HIDDEN);
    float4* dst = (float4*)(&sX[0][0]);
    #pragma unroll
    for (int i = 0; i < ROWS * HIDDEN / 4 / 128; i++)
        dst[tid + i * 128] = src[tid + i * 128];
    __syncthreads();

    float accQ[ROWS], accK[ROWS], accV[ROWS];
    #pragma unroll
    for (int r = 0; r < ROWS; r++) { accQ[r] = 0.f; accK[r] = 0.f; accV[r] = 0.f; }
    const int c = tid;
    for (int d = 0; d < HIDDEN; d++) {
        const float wq = Wq[d * HIDDEN + c];
        const float wk = Wk[d * HIDDEN + c];
        const float wv = Wv[d * HIDDEN + c];
        #pragma unroll
        for (int r = 0; r < ROWS; r++) {
            const float x = sX[r][d];
            accQ[r] = fmaf(x, wq, accQ[r]);
            accK[r] = fmaf(x, wk, accK[r]);
            accV[r] = fmaf(x, wv, accV[r]);
        }
    }
    const float bqv = bq[c], bkv = bk[c], bvv = bv[c];
    #pragma unroll
    for (int r = 0; r < ROWS; r++) {
        const int off = (row0 + r) * HIDDEN + c;
        Q[off] = accQ[r] + bqv;
        K[off] = accK[r] + bkv;
        V[off] = accV[r] + bvv;
    }
}

// ---------------- Kernel 2: fused attention ----------------
// Wave w owns k-rows [128w, 128w+128) in BOTH phase A (QK, pre-masked, +be)
// and phase B (edge bias -> sB, one row per wave-pass). Masked rows skip
// loads AND compute (whole-wave branch). Fold = 3 DPP adds, writer stores
// (no RMW). Softmax adds sS + sB once.
__global__ __launch_bounds__(256, 4) void attn_fused(
    const float* __restrict__ ef,     // [B][N][N][HIDDEN]
    const int*   __restrict__ mask,   // [B][N][N]
    const float* __restrict__ We,     // [HIDDEN][HEADS]
    const float* __restrict__ be,     // [HEADS]
    const float* __restrict__ Q, const float* __restrict__ K,
    const float* __restrict__ V,
    float* __restrict__ attn)         // [B*N][HIDDEN]
{
    __shared__ float sS[NSEQ * SROW];   // masked QK + be  -> softmax weights
    __shared__ float sB[NSEQ * SROW];   // edge bias (0 if masked); reused as sPd

    const int bq = blockIdx.x;          // b*512 + q
    const int b  = bq >> 9;
    const int tid = threadIdx.x;
    const int wvid = tid >> 6;          // wave 0..3
    const int lane = tid & 63;
    const int hsel = lane >> 3;         // head 0..7
    const int dseg = lane & 7;          // d in [16*dseg, 16*dseg+16)
    const bool wr8 = (dseg == 0);

    const int* mbase = mask + (size_t)bq * NSEQ;
    const float4* efb = (const float4*)(ef + (size_t)bq * NSEQ * HIDDEN);

    // rWe[j] = We[16*dseg + j][hsel], j = 0..15 (one-time, L2-hot)
    float rWe[16];
    #pragma unroll
    for (int j = 0; j < 16; j++)
        rWe[j] = We[(16 * dseg + j) * 8 + hsel];

    // ---- Phase A: wave-private QK^T, pre-masked, + be ----
    {
        const int ha = lane & 7;
        const int kk = lane >> 3;
        const float beh = be[ha];
        const float4* qp = (const float4*)(Q + (size_t)bq * HIDDEN + ha * HDIM);
        const float4 q0 = qp[0], q1 = qp[1], q2 = qp[2], q3 = qp[3];
        const int kb = 128 * wvid + kk;
        #pragma unroll 2
        for (int i = 0; i < 16; i++) {
            const int k = kb + 8 * i;
            const int mk = mbase[k];
            float sc = NEGINF;
            if (mk) {
                const float4* kp = (const float4*)(K + (size_t)(b * NSEQ + k) * HIDDEN + ha * HDIM);
                const float4 k0 = kp[0], k1 = kp[1], k2 = kp[2], k3 = kp[3];
                float p0 = q0.x * k0.x; p0 = fmaf(q0.y, k0.y, p0);
                p0 = fmaf(q0.z, k0.z, p0); p0 = fmaf(q0.w, k0.w, p0);
                float p1 = q1.x * k1.x; p1 = fmaf(q1.y, k1.y, p1);
                p1 = fmaf(q1.z, k1.z, p1); p1 = fmaf(q1.w, k1.w, p1);
                float p2 = q2.x * k2.x; p2 = fmaf(q2.y, k2.y, p2);
                p2 = fmaf(q2.z, k2.z, p2); p2 = fmaf(q2.w, k2.w, p2);
                float p3 = q3.x * k3.x; p3 = fmaf(q3.y, k3.y, p3);
                p3 = fmaf(q3.z, k3.z, p3); p3 = fmaf(q3.w, k3.w, p3);
                sc = fmaf((p0 + p1) + (p2 + p3), 0.25f, beh);  // 1/sqrt(16)
            }
            sS[k * SROW + ha] = sc;
        }
    }
    // no barrier: phase B same-wave rows

    // ---- Phase B: edge bias, one row per wave-pass, mask-skipped ----
    {
        const int rb = 128 * wvid;
        const int fbase = dseg * 4;     // float4 index within row

        // slot: compute row r from regs, store bias (0 if masked)
        auto slot = [&](int r, int mk, float4 e0, float4 e1, float4 e2, float4 e3) {
            float pb = 0.f;
            if (mk) {
                float p0 = e0.x * rWe[0];  p0 = fmaf(e0.y, rWe[1], p0);
                p0 = fmaf(e0.z, rWe[2], p0); p0 = fmaf(e0.w, rWe[3], p0);
                float p1 = e1.x * rWe[4];  p1 = fmaf(e1.y, rWe[5], p1);
                p1 = fmaf(e1.z, rWe[6], p1); p1 = fmaf(e1.w, rWe[7], p1);
                float p2 = e2.x * rWe[8];  p2 = fmaf(e2.y, rWe[9], p2);
                p2 = fmaf(e2.z, rWe[10], p2); p2 = fmaf(e2.w, rWe[11], p2);
                float p3 = e3.x * rWe[12]; p3 = fmaf(e3.y, rWe[13], p3);
                p3 = fmaf(e3.z, rWe[14], p3); p3 = fmaf(e3.w, rWe[15], p3);
                pb = (p0 + p1) + (p2 + p3);
                pb = dppadd<QUAD_X1>(pb);   // + dseg^1
                pb = dppadd<QUAD_X2>(pb);   // + dseg^2
                pb = dppadd<ROW_SHL4>(pb);  // + other quad (valid at dseg<4)
            }
            if (wr8) sB[r * SROW + hsel] = pb;
        };

        int mkA = mbase[rb + 0];
        int mkB = mbase[rb + 1];
        float4 a0, a1, a2, a3, b0, b1, b2, b3;
        if (mkA) {
            const float4* p = efb + (size_t)(rb + 0) * 32 + fbase;
            a0 = p[0]; a1 = p[1]; a2 = p[2]; a3 = p[3];
        }
        if (mkB) {
            const float4* p = efb + (size_t)(rb + 1) * 32 + fbase;
            b0 = p[0]; b1 = p[1]; b2 = p[2]; b3 = p[3];
        }
        for (int r = 0; r < 128; r += 2) {
            slot(rb + r, mkA, a0, a1, a2, a3);
            const int mk2 = (r + 2 < 128) ? mbase[rb + r + 2] : 0;
            if (mk2) {
                const float4* p = efb + (size_t)(rb + r + 2) * 32 + fbase;
                a0 = p[0]; a1 = p[1]; a2 = p[2]; a3 = p[3];
            }
            slot(rb + r + 1, mkB, b0, b1, b2, b3);
            const int mk3 = (r + 3 < 128) ? mbase[rb + r + 3] : 0;
            if (mk3) {
                const float4* p = efb + (size_t)(rb + r + 3) * 32 + fbase;
                b0 = p[0]; b1 = p[1]; b2 = p[2]; b3 = p[3];
            }
            mkA = mk2; mkB = mk3;
        }
    }
    __syncthreads();   // sS + sB complete

    // ---- Phase C: softmax per head (32 lanes/head), values in regs ----
    {
        const int h = tid >> 5;
        const int j = tid & 31;
        float v[16];
        #pragma unroll
        for (int i = 0; i < 16; i++)
            v[i] = sS[(j + 32 * i) * SROW + h] + sB[(j + 32 * i) * SROW + h];
        float m = v[0];
        #pragma unroll
        for (int i = 1; i < 16; i++) m = fmaxf(m, v[i]);
        #pragma unroll
        for (int off = 16; off >= 1; off >>= 1) m = fmaxf(m, __shfl_xor(m, off, 64));
        float sum = 0.f;
        float e[16];
        #pragma unroll
        for (int i = 0; i < 16; i++) {
            e[i] = (v[i] <= -1e29f) ? 0.f : __expf(v[i] - m);
            sum += e[i];
        }
        #pragma unroll
        for (int off = 16; off >= 1; off >>= 1) sum += __shfl_xor(sum, off, 64);
        const float rinv = (sum > 0.f) ? 1.f / sum : 0.f;
        #pragma unroll
        for (int i = 0; i < 16; i++)
            sS[(j + 32 * i) * SROW + h] = e[i] * rinv;
    }
    __syncthreads();

    // ---- Phase D: out[d] = sum_k w[k][h] * V[b,k,d] (sB reused as sPd) ----
    float* sPd = sB;
    {
        const int d4 = tid & 31;            // d = 4*d4
        const int kg = tid >> 5;            // 64 k's per group
        const int h = d4 >> 2;
        const float4* v4 = (const float4*)(V + (size_t)b * NSEQ * HIDDEN) + d4;
        float4 acc = make_float4(0.f, 0.f, 0.f, 0.f);
        const int k0 = kg * 64;
        #pragma unroll 4
        for (int k = k0; k < k0 + 64; k++) {
            const float wgt = sS[k * SROW + h];
            const float4 vv = v4[(size_t)k * 32];
            acc.x = fmaf(wgt, vv.x, acc.x);
            acc.y = fmaf(wgt, vv.y, acc.y);
            acc.z = fmaf(wgt, vv.z, acc.z);
            acc.w = fmaf(wgt, vv.w, acc.w);
        }
        *(float4*)(&sPd[kg * 132 + d4 * 4]) = acc;
    }
    __syncthreads();
    if (tid < HIDDEN) {
        float s = 0.f;
        #pragma unroll
        for (int g = 0; g < 8; g++) s += sPd[g * 132 + tid];
        attn[bq * HIDDEN + tid] = s;
    }
}

// ---------------- Kernel 3: output projection ----------------
__global__ __launch_bounds__(128) void out_proj(
    const float* __restrict__ attn,
    const float* __restrict__ Wo, const float* __restrict__ bo,
    float* __restrict__ out)
{
    const int ROWS = 8;
    __shared__ float sX[ROWS][HIDDEN];
    const int row0 = blockIdx.x * ROWS;
    const int tid = threadIdx.x;

    const float4* src = (const float4*)(attn + row0 * HIDDEN);
    float4* dst = (float4*)(&sX[0][0]);
    #pragma unroll
    for (int i = 0; i < ROWS * HIDDEN / 4 / 128; i++)
        dst[tid + i * 128] = src[tid + i * 128];
    __syncthreads();

    float acc[ROWS];
    #pragma unroll
    for (int r = 0; r < ROWS; r++) acc[r] = 0.f;
    const int c = tid;
    for (int d = 0; d < HIDDEN; d++) {
        const float w = Wo[d * HIDDEN + c];
        #pragma unroll
        for (int r = 0; r < ROWS; r++)
            acc[r] = fmaf(sX[r][d], w, acc[r]);
    }
    const float bov = bo[c];
    #pragma unroll
    for (int r = 0; r < ROWS; r++)
        out[(row0 + r) * HIDDEN + c] = acc[r] + bov;
}

extern "C" void kernel_launch(void* const* d_in, const int* in_sizes, int n_in,
                              void* d_out, int out_size, void* d_ws, size_t ws_size,
                              hipStream_t stream) {
    const float* node = (const float*)d_in[0];
    const float* ef   = (const float*)d_in[1];
    const int*   mask = (const int*)d_in[2];
    const float* Wq = (const float*)d_in[3];
    const float* bq = (const float*)d_in[4];
    const float* Wk = (const float*)d_in[5];
    const float* bk = (const float*)d_in[6];
    const float* Wv = (const float*)d_in[7];
    const float* bv = (const float*)d_in[8];
    const float* We = (const float*)d_in[9];
    const float* be = (const float*)d_in[10];
    const float* Wo = (const float*)d_in[11];
    const float* bo = (const float*)d_in[12];
    float* out = (float*)d_out;

    const int ROWS_TOT = NBATCH * NSEQ;              // 2048
    const int RC = ROWS_TOT * HIDDEN;                // 262144 floats
    float* Q = (float*)d_ws;
    float* K = Q + RC;
    float* V = K + RC;
    float* attn = V + RC;

    qkv_proj<<<ROWS_TOT / 8, 128, 0, stream>>>(node, Wq, bq, Wk, bk, Wv, bv, Q, K, V);
    attn_fused<<<ROWS_TOT, 256, 0, stream>>>(ef, mask, We, be, Q, K, V, attn);
    out_proj<<<ROWS_TOT / 8, 128, 0, stream>>>(attn, Wo, bo, out);
}

// Round 8
// 268.759 us; speedup vs baseline: 1.0155x; 1.0155x over previous
//
#include <hip/hip_runtime.h>
#include <math.h>

#define HIDDEN 128
#define HEADS 8
#define HDIM 16
#define NSEQ 512
#define NBATCH 4
#define SROW 9          // sS row stride: 9j mod 32 spans all banks in softmax
#define NEGINF (-1e30f)

// v += lane-permuted v (pure VALU DPP).
template <int CTRL>
__device__ __forceinline__ float dppadd(float v) {
    int s = __builtin_amdgcn_update_dpp(0, __float_as_int(v), CTRL, 0xF, 0xF, true);
    return v + __int_as_float(s);
}
#define QUAD_X1  0xB1   // quad_perm [1,0,3,2]
#define QUAD_X2  0x4E   // quad_perm [2,3,0,1]
#define ROW_SHL4 0x104  // + other quad; valid at dseg==0 (R7-verified fold)

// ---------------- Kernel 1: fused Q/K/V projection ----------------
__global__ __launch_bounds__(128) void qkv_proj(
    const float* __restrict__ node,
    const float* __restrict__ Wq, const float* __restrict__ bq,
    const float* __restrict__ Wk, const float* __restrict__ bk,
    const float* __restrict__ Wv, const float* __restrict__ bv,
    float* __restrict__ Q, float* __restrict__ K, float* __restrict__ V)
{
    const int ROWS = 8;
    __shared__ float sX[ROWS][HIDDEN];
    const int row0 = blockIdx.x * ROWS;
    const int tid = threadIdx.x;

    const float4* src = (const float4*)(node + row0 * HIDDEN);
    float4* dst = (float4*)(&sX[0][0]);
    #pragma unroll
    for (int i = 0; i < ROWS * HIDDEN / 4 / 128; i++)
        dst[tid + i * 128] = src[tid + i * 128];
    __syncthreads();

    float accQ[ROWS], accK[ROWS], accV[ROWS];
    #pragma unroll
    for (int r = 0; r < ROWS; r++) { accQ[r] = 0.f; accK[r] = 0.f; accV[r] = 0.f; }
    const int c = tid;
    for (int d = 0; d < HIDDEN; d++) {
        const float wq = Wq[d * HIDDEN + c];
        const float wk = Wk[d * HIDDEN + c];
        const float wv = Wv[d * HIDDEN + c];
        #pragma unroll
        for (int r = 0; r < ROWS; r++) {
            const float x = sX[r][d];
            accQ[r] = fmaf(x, wq, accQ[r]);
            accK[r] = fmaf(x, wk, accK[r]);
            accV[r] = fmaf(x, wv, accV[r]);
        }
    }
    const float bqv = bq[c], bkv = bk[c], bvv = bv[c];
    #pragma unroll
    for (int r = 0; r < ROWS; r++) {
        const int off = (row0 + r) * HIDDEN + c;
        Q[off] = accQ[r] + bqv;
        K[off] = accK[r] + bkv;
        V[off] = accV[r] + bvv;
    }
}

// ---------------- Kernel A: edge-bias stream (no LDS, no barriers) --------
// bias_t[bq][h][k] = dot(ef[bq,k,:], We[:,h])  (masked rows skipped).
// grid 8192: bid -> (bq = bid>>2, quarter = bid&3); wave w owns 32 rows.
// lane: h = lane>>3, dseg = lane&7 (16 d's). Fold: 3 DPP adds (R7-verified).
// 4-slot rolling register pipeline; mask branch is wave-uniform (readfirstlane).
__global__ __launch_bounds__(256, 4) void edge_bias(
    const float* __restrict__ ef,     // [B][N][N][HIDDEN]
    const int*   __restrict__ mask,   // [B][N][N]
    const float* __restrict__ We,     // [HIDDEN][HEADS]
    float* __restrict__ bias_t)       // [B*N][HEADS][NSEQ]
{
    const int bid = blockIdx.x;
    const int bq = bid >> 2;
    const int tid = threadIdx.x;
    const int wvid = tid >> 6;
    const int lane = tid & 63;
    const int hsel = lane >> 3;
    const int dseg = lane & 7;
    const int r0 = (bid & 3) * 128 + wvid * 32;

    const int* mbase = mask + (size_t)bq * NSEQ;
    const float* efb = ef + (size_t)bq * NSEQ * HIDDEN;
    float* bout = bias_t + ((size_t)bq * HEADS + hsel) * NSEQ;

    float rWe[16];
    #pragma unroll
    for (int j = 0; j < 16; j++)
        rWe[j] = We[(16 * dseg + j) * 8 + hsel];

    auto loadslot = [&](int r, int& mk, float4& e0, float4& e1, float4& e2, float4& e3) {
        mk = __builtin_amdgcn_readfirstlane(mbase[r]);
        if (mk) {
            const float4* p = (const float4*)(efb + (size_t)r * HIDDEN) + dseg * 4;
            e0 = p[0]; e1 = p[1]; e2 = p[2]; e3 = p[3];
        }
    };
    auto compslot = [&](int r, int mk, const float4& e0, const float4& e1,
                        const float4& e2, const float4& e3) {
        if (mk) {
            float p0 = e0.x * rWe[0];  p0 = fmaf(e0.y, rWe[1], p0);
            p0 = fmaf(e0.z, rWe[2], p0); p0 = fmaf(e0.w, rWe[3], p0);
            float p1 = e1.x * rWe[4];  p1 = fmaf(e1.y, rWe[5], p1);
            p1 = fmaf(e1.z, rWe[6], p1); p1 = fmaf(e1.w, rWe[7], p1);
            float p2 = e2.x * rWe[8];  p2 = fmaf(e2.y, rWe[9], p2);
            p2 = fmaf(e2.z, rWe[10], p2); p2 = fmaf(e2.w, rWe[11], p2);
            float p3 = e3.x * rWe[12]; p3 = fmaf(e3.y, rWe[13], p3);
            p3 = fmaf(e3.z, rWe[14], p3); p3 = fmaf(e3.w, rWe[15], p3);
            float pb = (p0 + p1) + (p2 + p3);
            pb = dppadd<QUAD_X1>(pb);
            pb = dppadd<QUAD_X2>(pb);
            pb = dppadd<ROW_SHL4>(pb);
            if (dseg == 0) bout[r] = pb;
        }
    };

    int mkA, mkB, mkC, mkD;
    float4 a0, a1, a2, a3, b0, b1, b2, b3;
    float4 c0, c1, c2, c3, d0, d1, d2, d3;
    loadslot(r0 + 0, mkA, a0, a1, a2, a3);
    loadslot(r0 + 1, mkB, b0, b1, b2, b3);
    loadslot(r0 + 2, mkC, c0, c1, c2, c3);
    loadslot(r0 + 3, mkD, d0, d1, d2, d3);

    #pragma unroll
    for (int i = 0; i < 32; i += 4) {
        compslot(r0 + i + 0, mkA, a0, a1, a2, a3);
        if (i + 4 < 32) loadslot(r0 + i + 4, mkA, a0, a1, a2, a3);
        compslot(r0 + i + 1, mkB, b0, b1, b2, b3);
        if (i + 5 < 32) loadslot(r0 + i + 5, mkB, b0, b1, b2, b3);
        compslot(r0 + i + 2, mkC, c0, c1, c2, c3);
        if (i + 6 < 32) loadslot(r0 + i + 6, mkC, c0, c1, c2, c3);
        compslot(r0 + i + 3, mkD, d0, d1, d2, d3);
        if (i + 7 < 32) loadslot(r0 + i + 7, mkD, d0, d1, d2, d3);
    }
}

// ---------------- Kernel B: QK + bias + softmax + PV ----------------
__global__ __launch_bounds__(256, 4) void attn_soft(
    const float* __restrict__ bias_t, // [B*N][HEADS][NSEQ]
    const int*   __restrict__ mask,   // [B][N][N]
    const float* __restrict__ be,     // [HEADS]
    const float* __restrict__ Q, const float* __restrict__ K,
    const float* __restrict__ V,
    float* __restrict__ attn)         // [B*N][HIDDEN]
{
    __shared__ float sS[NSEQ * SROW];   // masked QK + be -> weights
    __shared__ float sPd[8 * 132];      // PV partials

    const int bq = blockIdx.x;
    const int b  = bq >> 9;
    const int tid = threadIdx.x;
    const int wvid = tid >> 6;
    const int lane = tid & 63;

    const int* mbase = mask + (size_t)bq * NSEQ;

    // ---- Phase A: wave-private QK^T, pre-masked, + be (R6-verified) ----
    {
        const int ha = lane & 7;
        const int kk = lane >> 3;
        const float beh = be[ha];
        const float4* qp = (const float4*)(Q + (size_t)bq * HIDDEN + ha * HDIM);
        const float4 q0 = qp[0], q1 = qp[1], q2 = qp[2], q3 = qp[3];
        const int kb = 128 * wvid + kk;
        #pragma unroll 2
        for (int i = 0; i < 16; i++) {
            const int k = kb + 8 * i;
            const int mk = mbase[k];
            float sc = NEGINF;
            if (mk) {
                const float4* kp = (const float4*)(K + (size_t)(b * NSEQ + k) * HIDDEN + ha * HDIM);
                const float4 k0 = kp[0], k1 = kp[1], k2 = kp[2], k3 = kp[3];
                float p0 = q0.x * k0.x; p0 = fmaf(q0.y, k0.y, p0);
                p0 = fmaf(q0.z, k0.z, p0); p0 = fmaf(q0.w, k0.w, p0);
                float p1 = q1.x * k1.x; p1 = fmaf(q1.y, k1.y, p1);
                p1 = fmaf(q1.z, k1.z, p1); p1 = fmaf(q1.w, k1.w, p1);
                float p2 = q2.x * k2.x; p2 = fmaf(q2.y, k2.y, p2);
                p2 = fmaf(q2.z, k2.z, p2); p2 = fmaf(q2.w, k2.w, p2);
                float p3 = q3.x * k3.x; p3 = fmaf(q3.y, k3.y, p3);
                p3 = fmaf(q3.z, k3.z, p3); p3 = fmaf(q3.w, k3.w, p3);
                sc = fmaf((p0 + p1) + (p2 + p3), 0.25f, beh);  // 1/sqrt(16)
            }
            sS[k * SROW + ha] = sc;
        }
    }
    __syncthreads();

    // ---- Phase C: softmax per head; bias added inline (coalesced read) ----
    {
        const int h = tid >> 5;
        const int j = tid & 31;
        const float* brow = bias_t + ((size_t)bq * HEADS + h) * NSEQ;
        float v[16];
        #pragma unroll
        for (int i = 0; i < 16; i++)
            v[i] = sS[(j + 32 * i) * SROW + h] + brow[j + 32 * i];
        float m = v[0];
        #pragma unroll
        for (int i = 1; i < 16; i++) m = fmaxf(m, v[i]);
        #pragma unroll
        for (int off = 16; off >= 1; off >>= 1) m = fmaxf(m, __shfl_xor(m, off, 64));
        float sum = 0.f;
        float e[16];
        #pragma unroll
        for (int i = 0; i < 16; i++) {
            e[i] = (v[i] <= -1e29f) ? 0.f : __expf(v[i] - m);
            sum += e[i];
        }
        #pragma unroll
        for (int off = 16; off >= 1; off >>= 1) sum += __shfl_xor(sum, off, 64);
        const float rinv = (sum > 0.f) ? 1.f / sum : 0.f;
        #pragma unroll
        for (int i = 0; i < 16; i++)
            sS[(j + 32 * i) * SROW + h] = e[i] * rinv;
    }
    __syncthreads();

    // ---- Phase D: out[d] = sum_k w[k][h] * V[b,k,d] ----
    {
        const int d4 = tid & 31;            // d = 4*d4
        const int kg = tid >> 5;            // 64 k's per group
        const int h = d4 >> 2;
        const float4* v4 = (const float4*)(V + (size_t)b * NSEQ * HIDDEN) + d4;
        float4 acc = make_float4(0.f, 0.f, 0.f, 0.f);
        const int k0 = kg * 64;
        #pragma unroll 4
        for (int k = k0; k < k0 + 64; k++) {
            const float wgt = sS[k * SROW + h];
            const float4 vv = v4[(size_t)k * 32];
            acc.x = fmaf(wgt, vv.x, acc.x);
            acc.y = fmaf(wgt, vv.y, acc.y);
            acc.z = fmaf(wgt, vv.z, acc.z);
            acc.w = fmaf(wgt, vv.w, acc.w);
        }
        *(float4*)(&sPd[kg * 132 + d4 * 4]) = acc;
    }
    __syncthreads();
    if (tid < HIDDEN) {
        float s = 0.f;
        #pragma unroll
        for (int g = 0; g < 8; g++) s += sPd[g * 132 + tid];
        attn[bq * HIDDEN + tid] = s;
    }
}

// ---------------- Kernel 3: output projection ----------------
__global__ __launch_bounds__(128) void out_proj(
    const float* __restrict__ attn,
    const float* __restrict__ Wo, const float* __restrict__ bo,
    float* __restrict__ out)
{
    const int ROWS = 8;
    __shared__ float sX[ROWS][HIDDEN];
    const int row0 = blockIdx.x * ROWS;
    const int tid = threadIdx.x;

    const float4* src = (const float4*)(attn + row0 * HIDDEN);
    float4* dst = (float4*)(&sX[0][0]);
    #pragma unroll
    for (int i = 0; i < ROWS * HIDDEN / 4 / 128; i++)
        dst[tid + i * 128] = src[tid + i * 128];
    __syncthreads();

    float acc[ROWS];
    #pragma unroll
    for (int r = 0; r < ROWS; r++) acc[r] = 0.f;
    const int c = tid;
    for (int d = 0; d < HIDDEN; d++) {
        const float w = Wo[d * HIDDEN + c];
        #pragma unroll
        for (int r = 0; r < ROWS; r++)
            acc[r] = fmaf(sX[r][d], w, acc[r]);
    }
    const float bov = bo[c];
    #pragma unroll
    for (int r = 0; r < ROWS; r++)
        out[(row0 + r) * HIDDEN + c] = acc[r] + bov;
}

extern "C" void kernel_launch(void* const* d_in, const int* in_sizes, int n_in,
                              void* d_out, int out_size, void* d_ws, size_t ws_size,
                              hipStream_t stream) {
    const float* node = (const float*)d_in[0];
    const float* ef   = (const float*)d_in[1];
    const int*   mask = (const int*)d_in[2];
    const float* Wq = (const float*)d_in[3];
    const float* bq = (const float*)d_in[4];
    const float* Wk = (const float*)d_in[5];
    const float* bk = (const float*)d_in[6];
    const float* Wv = (const float*)d_in[7];
    const float* bv = (const float*)d_in[8];
    const float* We = (const float*)d_in[9];
    const float* be = (const float*)d_in[10];
    const float* Wo = (const float*)d_in[11];
    const float* bo = (const float*)d_in[12];
    float* out = (float*)d_out;

    const int ROWS_TOT = NBATCH * NSEQ;              // 2048
    const int RC = ROWS_TOT * HIDDEN;                // 262144 floats
    float* Q = (float*)d_ws;
    float* K = Q + RC;
    float* V = K + RC;
    float* attnb = V + RC;
    float* bias_t = attnb + RC;                      // 2048*8*512 floats = 32 MB

    edge_bias<<<ROWS_TOT * 4, 256, 0, stream>>>(ef, mask, We, bias_t);
    qkv_proj<<<ROWS_TOT / 8, 128, 0, stream>>>(node, Wq, bq, Wk, bk, Wv, bv, Q, K, V);
    attn_soft<<<ROWS_TOT, 256, 0, stream>>>(bias_t, mask, be, Q, K, V, attnb);
    out_proj<<<ROWS_TOT / 8, 128, 0, stream>>>(attnb, Wo, bo, out);
}

// Round 9
// 159.271 us; speedup vs baseline: 1.7136x; 1.6874x over previous
//
#include <hip/hip_runtime.h>
#include <math.h>

#define HIDDEN 128
#define HEADS 8
#define HDIM 16
#define NSEQ 512
#define NBATCH 4
#define SROW 9          // sS row stride: 9j mod 32 spans all banks in softmax
#define NEGINF (-1e30f)

typedef _Float16 half8 __attribute__((ext_vector_type(8)));
typedef float f32x4 __attribute__((ext_vector_type(4)));

// ---------------- Kernel 1: fused Q/K/V projection ----------------
__global__ __launch_bounds__(128) void qkv_proj(
    const float* __restrict__ node,
    const float* __restrict__ Wq, const float* __restrict__ bq,
    const float* __restrict__ Wk, const float* __restrict__ bk,
    const float* __restrict__ Wv, const float* __restrict__ bv,
    float* __restrict__ Q, float* __restrict__ K, float* __restrict__ V)
{
    const int ROWS = 8;
    __shared__ float sX[ROWS][HIDDEN];
    const int row0 = blockIdx.x * ROWS;
    const int tid = threadIdx.x;

    const float4* src = (const float4*)(node + row0 * HIDDEN);
    float4* dst = (float4*)(&sX[0][0]);
    #pragma unroll
    for (int i = 0; i < ROWS * HIDDEN / 4 / 128; i++)
        dst[tid + i * 128] = src[tid + i * 128];
    __syncthreads();

    float accQ[ROWS], accK[ROWS], accV[ROWS];
    #pragma unroll
    for (int r = 0; r < ROWS; r++) { accQ[r] = 0.f; accK[r] = 0.f; accV[r] = 0.f; }
    const int c = tid;
    for (int d = 0; d < HIDDEN; d++) {
        const float wq = Wq[d * HIDDEN + c];
        const float wk = Wk[d * HIDDEN + c];
        const float wv = Wv[d * HIDDEN + c];
        #pragma unroll
        for (int r = 0; r < ROWS; r++) {
            const float x = sX[r][d];
            accQ[r] = fmaf(x, wq, accQ[r]);
            accK[r] = fmaf(x, wk, accK[r]);
            accV[r] = fmaf(x, wv, accV[r]);
        }
    }
    const float bqv = bq[c], bkv = bk[c], bvv = bv[c];
    #pragma unroll
    for (int r = 0; r < ROWS; r++) {
        const int off = (row0 + r) * HIDDEN + c;
        Q[off] = accQ[r] + bqv;
        K[off] = accK[r] + bkv;
        V[off] = accV[r] + bvv;
    }
}

// ---------------- Kernel A: edge-bias via MFMA (no LDS, no barriers) ------
// bias_t[bq][h][k] = dot(ef[bq,k,:], We[:,h]). Tall-skinny GEMM, one 16-row
// k-tile per 4 MFMAs. A-fragment loaded DIRECTLY from global (lane: row=l&15,
// d = 32*ks + 8*(l>>4)..+8): wave's union = 16 rows x 128B contiguous -> 1x
// traffic, no replication, no LDS, no cross-lane fold. Masked rows: lanes
// predicated off -> no HBM requests, A-rows = 0. f16 in, f32 accumulate.
__global__ __launch_bounds__(256, 4) void edge_bias(
    const float* __restrict__ ef,     // [B][N][N][HIDDEN]
    const int*   __restrict__ mask,   // [B][N][N]
    const float* __restrict__ We,     // [HIDDEN][HEADS]
    float* __restrict__ bias_t)       // [B*N][HEADS][NSEQ]
{
    const int bid = blockIdx.x;       // 4096: (bq, half)
    const int bq = bid >> 1;
    const int halfsel = bid & 1;
    const int tid = threadIdx.x;
    const int wvid = tid >> 6;
    const int lane = tid & 63;
    const int row16 = lane & 15;      // A row within tile / C col (head)
    const int g = lane >> 4;          // k-chunk group 0..3
    const int h = row16;              // head for C writeback (h<8 valid)

    const float4* efb4 = (const float4*)(ef + (size_t)bq * NSEQ * HIDDEN);
    const int* mbase = mask + (size_t)bq * NSEQ;
    float* bout = bias_t + ((size_t)bq * HEADS + (h & 7)) * NSEQ;

    // B fragments (We), one per K-slice: lane holds We[32ks+8g+j][h], j=0..7
    half8 Bf0, Bf1, Bf2, Bf3;
    #pragma unroll
    for (int j = 0; j < 8; j++) {
        const int dbase = 8 * g + j;
        Bf0[j] = (_Float16)(h < 8 ? We[(dbase +  0) * 8 + h] : 0.f);
        Bf1[j] = (_Float16)(h < 8 ? We[(dbase + 32) * 8 + h] : 0.f);
        Bf2[j] = (_Float16)(h < 8 ? We[(dbase + 64) * 8 + h] : 0.f);
        Bf3[j] = (_Float16)(h < 8 ? We[(dbase + 96) * 8 + h] : 0.f);
    }

    // this wave's 4 tiles: k0(i) = halfsel*256 + wvid*64 + 16*i
    const int kb = halfsel * 256 + wvid * 64;
    const int mk0 = mbase[kb + 0 * 16 + row16];
    const int mk1 = mbase[kb + 1 * 16 + row16];
    const int mk2 = mbase[kb + 2 * 16 + row16];
    const int mk3 = mbase[kb + 3 * 16 + row16];

    const float4 z = make_float4(0.f, 0.f, 0.f, 0.f);

    auto LOAD = [&](int k0, int mk, float4& a0, float4& a1, float4& a2, float4& a3,
                    float4& a4, float4& a5, float4& a6, float4& a7) {
        a0 = z; a1 = z; a2 = z; a3 = z; a4 = z; a5 = z; a6 = z; a7 = z;
        const float4* p = efb4 + (size_t)(k0 + row16) * 32 + 2 * g;
        if (mk) {   // per-lane exec mask: masked rows issue NO requests
            a0 = p[0];  a1 = p[1];
            a2 = p[8];  a3 = p[9];
            a4 = p[16]; a5 = p[17];
            a6 = p[24]; a7 = p[25];
        }
    };
    auto COMP = [&](int k0, const float4& a0, const float4& a1, const float4& a2,
                    const float4& a3, const float4& a4, const float4& a5,
                    const float4& a6, const float4& a7) {
        f32x4 acc = {0.f, 0.f, 0.f, 0.f};
        half8 A;
        A[0]=(_Float16)a0.x; A[1]=(_Float16)a0.y; A[2]=(_Float16)a0.z; A[3]=(_Float16)a0.w;
        A[4]=(_Float16)a1.x; A[5]=(_Float16)a1.y; A[6]=(_Float16)a1.z; A[7]=(_Float16)a1.w;
        acc = __builtin_amdgcn_mfma_f32_16x16x32_f16(A, Bf0, acc, 0, 0, 0);
        A[0]=(_Float16)a2.x; A[1]=(_Float16)a2.y; A[2]=(_Float16)a2.z; A[3]=(_Float16)a2.w;
        A[4]=(_Float16)a3.x; A[5]=(_Float16)a3.y; A[6]=(_Float16)a3.z; A[7]=(_Float16)a3.w;
        acc = __builtin_amdgcn_mfma_f32_16x16x32_f16(A, Bf1, acc, 0, 0, 0);
        A[0]=(_Float16)a4.x; A[1]=(_Float16)a4.y; A[2]=(_Float16)a4.z; A[3]=(_Float16)a4.w;
        A[4]=(_Float16)a5.x; A[5]=(_Float16)a5.y; A[6]=(_Float16)a5.z; A[7]=(_Float16)a5.w;
        acc = __builtin_amdgcn_mfma_f32_16x16x32_f16(A, Bf2, acc, 0, 0, 0);
        A[0]=(_Float16)a6.x; A[1]=(_Float16)a6.y; A[2]=(_Float16)a6.z; A[3]=(_Float16)a6.w;
        A[4]=(_Float16)a7.x; A[5]=(_Float16)a7.y; A[6]=(_Float16)a7.z; A[7]=(_Float16)a7.w;
        acc = __builtin_amdgcn_mfma_f32_16x16x32_f16(A, Bf3, acc, 0, 0, 0);
        if (h < 8) {    // C: col=lane&15 -> head, row=4g+reg -> k0+4g..+3
            float4 o = make_float4(acc[0], acc[1], acc[2], acc[3]);
            *(float4*)(bout + k0 + 4 * g) = o;
        }
    };

    float4 x0, x1, x2, x3, x4, x5, x6, x7;   // even tiles
    float4 y0, y1, y2, y3, y4, y5, y6, y7;   // odd tiles

    LOAD(kb +  0, mk0, x0, x1, x2, x3, x4, x5, x6, x7);
    LOAD(kb + 16, mk1, y0, y1, y2, y3, y4, y5, y6, y7);
    COMP(kb +  0, x0, x1, x2, x3, x4, x5, x6, x7);
    LOAD(kb + 32, mk2, x0, x1, x2, x3, x4, x5, x6, x7);
    COMP(kb + 16, y0, y1, y2, y3, y4, y5, y6, y7);
    LOAD(kb + 48, mk3, y0, y1, y2, y3, y4, y5, y6, y7);
    COMP(kb + 32, x0, x1, x2, x3, x4, x5, x6, x7);
    COMP(kb + 48, y0, y1, y2, y3, y4, y5, y6, y7);
}

// ---------------- Kernel B: QK + bias + softmax + PV ----------------
__global__ __launch_bounds__(256, 4) void attn_soft(
    const float* __restrict__ bias_t, // [B*N][HEADS][NSEQ]
    const int*   __restrict__ mask,   // [B][N][N]
    const float* __restrict__ be,     // [HEADS]
    const float* __restrict__ Q, const float* __restrict__ K,
    const float* __restrict__ V,
    float* __restrict__ attn)         // [B*N][HIDDEN]
{
    __shared__ float sS[NSEQ * SROW];   // masked QK + be -> weights
    __shared__ float sPd[8 * 132];      // PV partials

    const int bq = blockIdx.x;
    const int b  = bq >> 9;
    const int tid = threadIdx.x;
    const int wvid = tid >> 6;
    const int lane = tid & 63;

    const int* mbase = mask + (size_t)bq * NSEQ;

    // ---- Phase A: wave-private QK^T, pre-masked, + be ----
    {
        const int ha = lane & 7;
        const int kk = lane >> 3;
        const float beh = be[ha];
        const float4* qp = (const float4*)(Q + (size_t)bq * HIDDEN + ha * HDIM);
        const float4 q0 = qp[0], q1 = qp[1], q2 = qp[2], q3 = qp[3];
        const int kb = 128 * wvid + kk;
        #pragma unroll 2
        for (int i = 0; i < 16; i++) {
            const int k = kb + 8 * i;
            const int mk = mbase[k];
            float sc = NEGINF;
            if (mk) {
                const float4* kp = (const float4*)(K + (size_t)(b * NSEQ + k) * HIDDEN + ha * HDIM);
                const float4 k0 = kp[0], k1 = kp[1], k2 = kp[2], k3 = kp[3];
                float p0 = q0.x * k0.x; p0 = fmaf(q0.y, k0.y, p0);
                p0 = fmaf(q0.z, k0.z, p0); p0 = fmaf(q0.w, k0.w, p0);
                float p1 = q1.x * k1.x; p1 = fmaf(q1.y, k1.y, p1);
                p1 = fmaf(q1.z, k1.z, p1); p1 = fmaf(q1.w, k1.w, p1);
                float p2 = q2.x * k2.x; p2 = fmaf(q2.y, k2.y, p2);
                p2 = fmaf(q2.z, k2.z, p2); p2 = fmaf(q2.w, k2.w, p2);
                float p3 = q3.x * k3.x; p3 = fmaf(q3.y, k3.y, p3);
                p3 = fmaf(q3.z, k3.z, p3); p3 = fmaf(q3.w, k3.w, p3);
                sc = fmaf((p0 + p1) + (p2 + p3), 0.25f, beh);  // 1/sqrt(16)
            }
            sS[k * SROW + ha] = sc;
        }
    }
    __syncthreads();

    // ---- Phase C: softmax per head; bias added inline (coalesced read) ----
    {
        const int h = tid >> 5;
        const int j = tid & 31;
        const float* brow = bias_t + ((size_t)bq * HEADS + h) * NSEQ;
        float v[16];
        #pragma unroll
        for (int i = 0; i < 16; i++)
            v[i] = sS[(j + 32 * i) * SROW + h] + brow[j + 32 * i];
        float m = v[0];
        #pragma unroll
        for (int i = 1; i < 16; i++) m = fmaxf(m, v[i]);
        #pragma unroll
        for (int off = 16; off >= 1; off >>= 1) m = fmaxf(m, __shfl_xor(m, off, 64));
        float sum = 0.f;
        float e[16];
        #pragma unroll
        for (int i = 0; i < 16; i++) {
            e[i] = (v[i] <= -1e29f) ? 0.f : __expf(v[i] - m);
            sum += e[i];
        }
        #pragma unroll
        for (int off = 16; off >= 1; off >>= 1) sum += __shfl_xor(sum, off, 64);
        const float rinv = (sum > 0.f) ? 1.f / sum : 0.f;
        #pragma unroll
        for (int i = 0; i < 16; i++)
            sS[(j + 32 * i) * SROW + h] = e[i] * rinv;
    }
    __syncthreads();

    // ---- Phase D: out[d] = sum_k w[k][h] * V[b,k,d] ----
    {
        const int d4 = tid & 31;            // d = 4*d4
        const int kg = tid >> 5;            // 64 k's per group
        const int h = d4 >> 2;
        const float4* v4 = (const float4*)(V + (size_t)b * NSEQ * HIDDEN) + d4;
        float4 acc = make_float4(0.f, 0.f, 0.f, 0.f);
        const int k0 = kg * 64;
        #pragma unroll 4
        for (int k = k0; k < k0 + 64; k++) {
            const float wgt = sS[k * SROW + h];
            const float4 vv = v4[(size_t)k * 32];
            acc.x = fmaf(wgt, vv.x, acc.x);
            acc.y = fmaf(wgt, vv.y, acc.y);
            acc.z = fmaf(wgt, vv.z, acc.z);
            acc.w = fmaf(wgt, vv.w, acc.w);
        }
        *(float4*)(&sPd[kg * 132 + d4 * 4]) = acc;
    }
    __syncthreads();
    if (tid < HIDDEN) {
        float s = 0.f;
        #pragma unroll
        for (int g = 0; g < 8; g++) s += sPd[g * 132 + tid];
        attn[bq * HIDDEN + tid] = s;
    }
}

// ---------------- Kernel 3: output projection ----------------
__global__ __launch_bounds__(128) void out_proj(
    const float* __restrict__ attn,
    const float* __restrict__ Wo, const float* __restrict__ bo,
    float* __restrict__ out)
{
    const int ROWS = 8;
    __shared__ float sX[ROWS][HIDDEN];
    const int row0 = blockIdx.x * ROWS;
    const int tid = threadIdx.x;

    const float4* src = (const float4*)(attn + row0 * HIDDEN);
    float4* dst = (float4*)(&sX[0][0]);
    #pragma unroll
    for (int i = 0; i < ROWS * HIDDEN / 4 / 128; i++)
        dst[tid + i * 128] = src[tid + i * 128];
    __syncthreads();

    float acc[ROWS];
    #pragma unroll
    for (int r = 0; r < ROWS; r++) acc[r] = 0.f;
    const int c = tid;
    for (int d = 0; d < HIDDEN; d++) {
        const float w = Wo[d * HIDDEN + c];
        #pragma unroll
        for (int r = 0; r < ROWS; r++)
            acc[r] = fmaf(sX[r][d], w, acc[r]);
    }
    const float bov = bo[c];
    #pragma unroll
    for (int r = 0; r < ROWS; r++)
        out[(row0 + r) * HIDDEN + c] = acc[r] + bov;
}

extern "C" void kernel_launch(void* const* d_in, const int* in_sizes, int n_in,
                              void* d_out, int out_size, void* d_ws, size_t ws_size,
                              hipStream_t stream) {
    const float* node = (const float*)d_in[0];
    const float* ef   = (const float*)d_in[1];
    const int*   mask = (const int*)d_in[2];
    const float* Wq = (const float*)d_in[3];
    const float* bq = (const float*)d_in[4];
    const float* Wk = (const float*)d_in[5];
    const float* bk = (const float*)d_in[6];
    const float* Wv = (const float*)d_in[7];
    const float* bv = (const float*)d_in[8];
    const float* We = (const float*)d_in[9];
    const float* be = (const float*)d_in[10];
    const float* Wo = (const float*)d_in[11];
    const float* bo = (const float*)d_in[12];
    float* out = (float*)d_out;

    const int ROWS_TOT = NBATCH * NSEQ;              // 2048
    const int RC = ROWS_TOT * HIDDEN;                // 262144 floats
    float* Q = (float*)d_ws;
    float* K = Q + RC;
    float* V = K + RC;
    float* attnb = V + RC;
    float* bias_t = attnb + RC;                      // 2048*8*512 floats = 32 MB

    edge_bias<<<ROWS_TOT * 2, 256, 0, stream>>>(ef, mask, We, bias_t);
    qkv_proj<<<ROWS_TOT / 8, 128, 0, stream>>>(node, Wq, bq, Wk, bk, Wv, bv, Q, K, V);
    attn_soft<<<ROWS_TOT, 256, 0, stream>>>(bias_t, mask, be, Q, K, V, attnb);
    out_proj<<<ROWS_TOT / 8, 128, 0, stream>>>(attnb, Wo, bo, out);
}

// Round 10
// 140.225 us; speedup vs baseline: 1.9463x; 1.1358x over previous
//
#include <hip/hip_runtime.h>
#include <math.h>

#define HIDDEN 128
#define HEADS 8
#define HDIM 16
#define NSEQ 512
#define NBATCH 4
#define SROW 9          // sS/sB row stride: 9j mod 32 spans all banks in softmax
#define NEGINF (-1e30f)

typedef _Float16 half8 __attribute__((ext_vector_type(8)));
typedef float f32x4 __attribute__((ext_vector_type(4)));

// ---------------- Kernel 1: fused Q/K/V projection ----------------
__global__ __launch_bounds__(128) void qkv_proj(
    const float* __restrict__ node,
    const float* __restrict__ Wq, const float* __restrict__ bq,
    const float* __restrict__ Wk, const float* __restrict__ bk,
    const float* __restrict__ Wv, const float* __restrict__ bv,
    float* __restrict__ Q, float* __restrict__ K, float* __restrict__ V)
{
    const int ROWS = 8;
    __shared__ float sX[ROWS][HIDDEN];
    const int row0 = blockIdx.x * ROWS;
    const int tid = threadIdx.x;

    const float4* src = (const float4*)(node + row0 * HIDDEN);
    float4* dst = (float4*)(&sX[0][0]);
    #pragma unroll
    for (int i = 0; i < ROWS * HIDDEN / 4 / 128; i++)
        dst[tid + i * 128] = src[tid + i * 128];
    __syncthreads();

    float accQ[ROWS], accK[ROWS], accV[ROWS];
    #pragma unroll
    for (int r = 0; r < ROWS; r++) { accQ[r] = 0.f; accK[r] = 0.f; accV[r] = 0.f; }
    const int c = tid;
    for (int d = 0; d < HIDDEN; d++) {
        const float wq = Wq[d * HIDDEN + c];
        const float wk = Wk[d * HIDDEN + c];
        const float wv = Wv[d * HIDDEN + c];
        #pragma unroll
        for (int r = 0; r < ROWS; r++) {
            const float x = sX[r][d];
            accQ[r] = fmaf(x, wq, accQ[r]);
            accK[r] = fmaf(x, wk, accK[r]);
            accV[r] = fmaf(x, wv, accV[r]);
        }
    }
    const float bqv = bq[c], bkv = bk[c], bvv = bv[c];
    #pragma unroll
    for (int r = 0; r < ROWS; r++) {
        const int off = (row0 + r) * HIDDEN + c;
        Q[off] = accQ[r] + bqv;
        K[off] = accK[r] + bkv;
        V[off] = accV[r] + bvv;
    }
}

// ---------------- Kernel 2: fused attention (R9 MFMA bias engine inlined) --
// Block = (b,q). Wave w owns k in [128w,128w+128) for BOTH QK^T (-> sS) and
// the 8 MFMA bias tiles (-> sB, plain stores). A-fragments loaded DIRECTLY
// from global (wave union = 16 rows x 128B, 1x traffic); masked rows: lanes
// exec-predicated off -> zero A rows, no HBM requests. 2-deep X/Y pipeline
// with QK iters as latency cover. Zero barriers until softmax.
__global__ __launch_bounds__(256, 3) void attn_fused(
    const float* __restrict__ ef,     // [B][N][N][HIDDEN]
    const int*   __restrict__ mask,   // [B][N][N]
    const float* __restrict__ We,     // [HIDDEN][HEADS]
    const float* __restrict__ be,     // [HEADS]
    const float* __restrict__ Q, const float* __restrict__ K,
    const float* __restrict__ V,
    float* __restrict__ attn)         // [B*N][HIDDEN]
{
    __shared__ float sS[NSEQ * SROW];   // masked QK + be -> weights
    __shared__ float sB[NSEQ * SROW];   // edge bias; reused as sPd after softmax

    const int bq = blockIdx.x;
    const int b  = bq >> 9;
    const int tid = threadIdx.x;
    const int wvid = tid >> 6;
    const int lane = tid & 63;
    const int row16 = lane & 15;        // A row within tile / C col (head)
    const int g = lane >> 4;            // k-slice group 0..3
    const int h = row16;                // head for sB writeback (h<8 valid)
    const int kb = 128 * wvid;          // wave's k range base

    const float4* efb4 = (const float4*)(ef + (size_t)bq * NSEQ * HIDDEN);
    const int* mbase = mask + (size_t)bq * NSEQ;

    // per-lane tile masks (row predicate for the A-fragment loads)
    const int m0 = mbase[kb +  0 + row16];
    const int m1 = mbase[kb + 16 + row16];
    const int m2 = mbase[kb + 32 + row16];
    const int m3 = mbase[kb + 48 + row16];
    const int m4 = mbase[kb + 64 + row16];
    const int m5 = mbase[kb + 80 + row16];
    const int m6 = mbase[kb + 96 + row16];
    const int m7 = mbase[kb + 112 + row16];

    const float4 z = make_float4(0.f, 0.f, 0.f, 0.f);
    auto LOAD = [&](int k0, int mk, float4& a0, float4& a1, float4& a2, float4& a3,
                    float4& a4, float4& a5, float4& a6, float4& a7) {
        a0 = z; a1 = z; a2 = z; a3 = z; a4 = z; a5 = z; a6 = z; a7 = z;
        const float4* p = efb4 + (size_t)(k0 + row16) * 32 + 2 * g;
        if (mk) {   // exec-masked: no requests for masked rows
            a0 = p[0];  a1 = p[1];
            a2 = p[8];  a3 = p[9];
            a4 = p[16]; a5 = p[17];
            a6 = p[24]; a7 = p[25];
        }
    };

    // B fragments (We): lane holds We[32*ks + 8g + j][h], j=0..7
    half8 Bf0, Bf1, Bf2, Bf3;
    #pragma unroll
    for (int j = 0; j < 8; j++) {
        const int dbase = 8 * g + j;
        Bf0[j] = (_Float16)(h < 8 ? We[(dbase +  0) * 8 + h] : 0.f);
        Bf1[j] = (_Float16)(h < 8 ? We[(dbase + 32) * 8 + h] : 0.f);
        Bf2[j] = (_Float16)(h < 8 ? We[(dbase + 64) * 8 + h] : 0.f);
        Bf3[j] = (_Float16)(h < 8 ? We[(dbase + 96) * 8 + h] : 0.f);
    }

    auto COMP = [&](int k0, const float4& a0, const float4& a1, const float4& a2,
                    const float4& a3, const float4& a4, const float4& a5,
                    const float4& a6, const float4& a7) {
        f32x4 acc = {0.f, 0.f, 0.f, 0.f};
        half8 A;
        A[0]=(_Float16)a0.x; A[1]=(_Float16)a0.y; A[2]=(_Float16)a0.z; A[3]=(_Float16)a0.w;
        A[4]=(_Float16)a1.x; A[5]=(_Float16)a1.y; A[6]=(_Float16)a1.z; A[7]=(_Float16)a1.w;
        acc = __builtin_amdgcn_mfma_f32_16x16x32_f16(A, Bf0, acc, 0, 0, 0);
        A[0]=(_Float16)a2.x; A[1]=(_Float16)a2.y; A[2]=(_Float16)a2.z; A[3]=(_Float16)a2.w;
        A[4]=(_Float16)a3.x; A[5]=(_Float16)a3.y; A[6]=(_Float16)a3.z; A[7]=(_Float16)a3.w;
        acc = __builtin_amdgcn_mfma_f32_16x16x32_f16(A, Bf1, acc, 0, 0, 0);
        A[0]=(_Float16)a4.x; A[1]=(_Float16)a4.y; A[2]=(_Float16)a4.z; A[3]=(_Float16)a4.w;
        A[4]=(_Float16)a5.x; A[5]=(_Float16)a5.y; A[6]=(_Float16)a5.z; A[7]=(_Float16)a5.w;
        acc = __builtin_amdgcn_mfma_f32_16x16x32_f16(A, Bf2, acc, 0, 0, 0);
        A[0]=(_Float16)a6.x; A[1]=(_Float16)a6.y; A[2]=(_Float16)a6.z; A[3]=(_Float16)a6.w;
        A[4]=(_Float16)a7.x; A[5]=(_Float16)a7.y; A[6]=(_Float16)a7.z; A[7]=(_Float16)a7.w;
        acc = __builtin_amdgcn_mfma_f32_16x16x32_f16(A, Bf3, acc, 0, 0, 0);
        if (h < 8) {    // C: col=lane&15=head, row=4g+reg -> k = k0+4g+reg
            float* sp = &sB[(k0 + 4 * g) * SROW + h];
            sp[0 * SROW] = acc[0];
            sp[1 * SROW] = acc[1];
            sp[2 * SROW] = acc[2];
            sp[3 * SROW] = acc[3];
        }
    };

    // QK^T setup (same wave's rows; writes sS; adds be; pre-masked)
    const int ha = lane & 7;
    const int kk = lane >> 3;
    const float beh = be[ha];
    const float4* qp = (const float4*)(Q + (size_t)bq * HIDDEN + ha * HDIM);
    const float4 q0 = qp[0], q1 = qp[1], q2 = qp[2], q3 = qp[3];
    auto QKI = [&](int i) {
        const int k = kb + kk + 8 * i;
        const int mk = mbase[k];
        float sc = NEGINF;
        if (mk) {
            const float4* kp = (const float4*)(K + (size_t)(b * NSEQ + k) * HIDDEN + ha * HDIM);
            const float4 k0 = kp[0], k1 = kp[1], k2 = kp[2], k3 = kp[3];
            float p0 = q0.x * k0.x; p0 = fmaf(q0.y, k0.y, p0);
            p0 = fmaf(q0.z, k0.z, p0); p0 = fmaf(q0.w, k0.w, p0);
            float p1 = q1.x * k1.x; p1 = fmaf(q1.y, k1.y, p1);
            p1 = fmaf(q1.z, k1.z, p1); p1 = fmaf(q1.w, k1.w, p1);
            float p2 = q2.x * k2.x; p2 = fmaf(q2.y, k2.y, p2);
            p2 = fmaf(q2.z, k2.z, p2); p2 = fmaf(q2.w, k2.w, p2);
            float p3 = q3.x * k3.x; p3 = fmaf(q3.y, k3.y, p3);
            p3 = fmaf(q3.z, k3.z, p3); p3 = fmaf(q3.w, k3.w, p3);
            sc = fmaf((p0 + p1) + (p2 + p3), 0.25f, beh);  // 1/sqrt(16)
        }
        sS[k * SROW + ha] = sc;
    };

    // ---- pipeline: t0,t1 loads in flight; 8 QK iters as latency cover;
    //      then {QKI; COMP(t_s); LOAD(t_{s+2})} 2-deep rotation ----
    float4 x0, x1, x2, x3, x4, x5, x6, x7;
    float4 y0, y1, y2, y3, y4, y5, y6, y7;

    LOAD(kb +  0, m0, x0, x1, x2, x3, x4, x5, x6, x7);
    LOAD(kb + 16, m1, y0, y1, y2, y3, y4, y5, y6, y7);
    QKI(0); QKI(1); QKI(2); QKI(3); QKI(4); QKI(5); QKI(6); QKI(7);

    QKI(8);
    COMP(kb + 0, x0, x1, x2, x3, x4, x5, x6, x7);
    LOAD(kb + 32, m2, x0, x1, x2, x3, x4, x5, x6, x7);
    QKI(9);
    COMP(kb + 16, y0, y1, y2, y3, y4, y5, y6, y7);
    LOAD(kb + 48, m3, y0, y1, y2, y3, y4, y5, y6, y7);
    QKI(10);
    COMP(kb + 32, x0, x1, x2, x3, x4, x5, x6, x7);
    LOAD(kb + 64, m4, x0, x1, x2, x3, x4, x5, x6, x7);
    QKI(11);
    COMP(kb + 48, y0, y1, y2, y3, y4, y5, y6, y7);
    LOAD(kb + 80, m5, y0, y1, y2, y3, y4, y5, y6, y7);
    QKI(12);
    COMP(kb + 64, x0, x1, x2, x3, x4, x5, x6, x7);
    LOAD(kb + 96, m6, x0, x1, x2, x3, x4, x5, x6, x7);
    QKI(13);
    COMP(kb + 80, y0, y1, y2, y3, y4, y5, y6, y7);
    LOAD(kb + 112, m7, y0, y1, y2, y3, y4, y5, y6, y7);
    QKI(14);
    COMP(kb + 96, x0, x1, x2, x3, x4, x5, x6, x7);
    QKI(15);
    COMP(kb + 112, y0, y1, y2, y3, y4, y5, y6, y7);

    __syncthreads();   // the ONE barrier before softmax

    // ---- softmax per head (32 lanes/head); score = sS + sB ----
    {
        const int hh = tid >> 5;
        const int j = tid & 31;
        float v[16];
        #pragma unroll
        for (int i = 0; i < 16; i++)
            v[i] = sS[(j + 32 * i) * SROW + hh] + sB[(j + 32 * i) * SROW + hh];
        float m = v[0];
        #pragma unroll
        for (int i = 1; i < 16; i++) m = fmaxf(m, v[i]);
        #pragma unroll
        for (int off = 16; off >= 1; off >>= 1) m = fmaxf(m, __shfl_xor(m, off, 64));
        float sum = 0.f;
        float e[16];
        #pragma unroll
        for (int i = 0; i < 16; i++) {
            e[i] = (v[i] <= -1e29f) ? 0.f : __expf(v[i] - m);
            sum += e[i];
        }
        #pragma unroll
        for (int off = 16; off >= 1; off >>= 1) sum += __shfl_xor(sum, off, 64);
        const float rinv = (sum > 0.f) ? 1.f / sum : 0.f;
        #pragma unroll
        for (int i = 0; i < 16; i++)
            sS[(j + 32 * i) * SROW + hh] = e[i] * rinv;
    }
    __syncthreads();

    // ---- PV: out[d] = sum_k w[k][h] * V[b,k,d] (sB reused as partials) ----
    float* sPd = sB;
    {
        const int d4 = tid & 31;            // d = 4*d4
        const int kg = tid >> 5;            // 64 k's per group
        const int hh = d4 >> 2;
        const float4* v4 = (const float4*)(V + (size_t)b * NSEQ * HIDDEN) + d4;
        float4 acc = make_float4(0.f, 0.f, 0.f, 0.f);
        const int k0 = kg * 64;
        #pragma unroll 4
        for (int k = k0; k < k0 + 64; k++) {
            const float wgt = sS[k * SROW + hh];
            const float4 vv = v4[(size_t)k * 32];
            acc.x = fmaf(wgt, vv.x, acc.x);
            acc.y = fmaf(wgt, vv.y, acc.y);
            acc.z = fmaf(wgt, vv.z, acc.z);
            acc.w = fmaf(wgt, vv.w, acc.w);
        }
        *(float4*)(&sPd[kg * 132 + d4 * 4]) = acc;
    }
    __syncthreads();
    if (tid < HIDDEN) {
        float s = 0.f;
        #pragma unroll
        for (int gg = 0; gg < 8; gg++) s += sPd[gg * 132 + tid];
        attn[bq * HIDDEN + tid] = s;
    }
}

// ---------------- Kernel 3: output projection ----------------
__global__ __launch_bounds__(128) void out_proj(
    const float* __restrict__ attn,
    const float* __restrict__ Wo, const float* __restrict__ bo,
    float* __restrict__ out)
{
    const int ROWS = 8;
    __shared__ float sX[ROWS][HIDDEN];
    const int row0 = blockIdx.x * ROWS;
    const int tid = threadIdx.x;

    const float4* src = (const float4*)(attn + row0 * HIDDEN);
    float4* dst = (float4*)(&sX[0][0]);
    #pragma unroll
    for (int i = 0; i < ROWS * HIDDEN / 4 / 128; i++)
        dst[tid + i * 128] = src[tid + i * 128];
    __syncthreads();

    float acc[ROWS];
    #pragma unroll
    for (int r = 0; r < ROWS; r++) acc[r] = 0.f;
    const int c = tid;
    for (int d = 0; d < HIDDEN; d++) {
        const float w = Wo[d * HIDDEN + c];
        #pragma unroll
        for (int r = 0; r < ROWS; r++)
            acc[r] = fmaf(sX[r][d], w, acc[r]);
    }
    const float bov = bo[c];
    #pragma unroll
    for (int r = 0; r < ROWS; r++)
        out[(row0 + r) * HIDDEN + c] = acc[r] + bov;
}

extern "C" void kernel_launch(void* const* d_in, const int* in_sizes, int n_in,
                              void* d_out, int out_size, void* d_ws, size_t ws_size,
                              hipStream_t stream) {
    const float* node = (const float*)d_in[0];
    const float* ef   = (const float*)d_in[1];
    const int*   mask = (const int*)d_in[2];
    const float* Wq = (const float*)d_in[3];
    const float* bq = (const float*)d_in[4];
    const float* Wk = (const float*)d_in[5];
    const float* bk = (const float*)d_in[6];
    const float* Wv = (const float*)d_in[7];
    const float* bv = (const float*)d_in[8];
    const float* We = (const float*)d_in[9];
    const float* be = (const float*)d_in[10];
    const float* Wo = (const float*)d_in[11];
    const float* bo = (const float*)d_in[12];
    float* out = (float*)d_out;

    const int ROWS_TOT = NBATCH * NSEQ;              // 2048
    const int RC = ROWS_TOT * HIDDEN;                // 262144 floats
    float* Q = (float*)d_ws;
    float* K = Q + RC;
    float* V = K + RC;
    float* attnb = V + RC;

    qkv_proj<<<ROWS_TOT / 8, 128, 0, stream>>>(node, Wq, bq, Wk, bk, Wv, bv, Q, K, V);
    attn_fused<<<ROWS_TOT, 256, 0, stream>>>(ef, mask, We, be, Q, K, V, attnb);
    out_proj<<<ROWS_TOT / 8, 128, 0, stream>>>(attnb, Wo, bo, out);
}